// Round 5
// baseline (90.112 us; speedup 1.0000x reference)
//
#include <hip/hip_runtime.h>
#include <math.h>

constexpr int H = 1024;
constexpr int V = 50257;
constexpr int L = 64;

constexpr int NB   = 1024;              // 4 blocks/CU
constexpr int NT   = 512;               // 8 waves/block -> 32 waves/CU
constexpr int NGRP = 64;                // 16 blocks per barrier group
constexpr int RPB  = 50;                // ceil(V/NB) rows per block in S4

// ---- barrier region (uints, 64B-strided, zeroed per call) -----------------
constexpr int BAR_ROOT  = 4 * NGRP * 16;        // leaf: (slot*NGRP+g)*16
constexpr int BAR_REL   = BAR_ROOT + 4 * 16;
constexpr int BAR_UINTS = BAR_REL + NGRP * 16;  // 5184 uints

// ---- ws float offsets ------------------------------------------------------
constexpr int OFF_WE   = BAR_UINTS;        // 64   attn logits, emb half
constexpr int OFF_WH   = OFF_WE + 64;      // 64   attn logits, hid half
constexpr int OFF_GH   = OFF_WH + 64;      // 3072 gh
constexpr int OFF_CP   = OFF_GH + 3 * H;   // 1024 comb emb-half partial
constexpr int OFF_X    = OFF_CP + H;       // 1024 x = relu(comb)
constexpr int OFF_HN   = OFF_X + H;        // 1024 h_new (coherent copy)
constexpr int OFF_PAIR = OFF_HN + H;       // 2*NB (m,s) partials

__device__ __forceinline__ void gput(float* p, float v) {
    __hip_atomic_store(p, v, __ATOMIC_RELAXED, __HIP_MEMORY_SCOPE_AGENT);
}
__device__ __forceinline__ float gget(const float* p) {
    return __hip_atomic_load(p, __ATOMIC_RELAXED, __HIP_MEMORY_SCOPE_AGENT);
}
__device__ __forceinline__ unsigned uget(const unsigned* p) {
    return __hip_atomic_load(p, __ATOMIC_RELAXED, __HIP_MEMORY_SCOPE_AGENT);
}

__device__ __forceinline__ float wsum(float v) {
#pragma unroll
    for (int off = 32; off > 0; off >>= 1) v += __shfl_xor(v, off);
    return v;
}
__device__ __forceinline__ float wmax(float v) {
#pragma unroll
    for (int off = 32; off > 0; off >>= 1) v = fmaxf(v, __shfl_xor(v, off));
    return v;
}

__device__ __forceinline__ float dot1024(const float* __restrict__ w,
                                         const float* __restrict__ v,
                                         int lane) {
    const float4* w4 = reinterpret_cast<const float4*>(w);
    const float4* v4 = reinterpret_cast<const float4*>(v);
    float acc = 0.f;
#pragma unroll
    for (int it = 0; it < 4; ++it) {
        const float4 a = w4[lane + it * 64];
        const float4 b = v4[lane + it * 64];
        acc += a.x * b.x + a.y * b.y + a.z * b.z + a.w * b.w;
    }
    return acc;
}

// Two rows at once: 8 global dwordx4 in flight before any reduce.
__device__ __forceinline__ void dot1024x2(const float* __restrict__ wa,
                                          const float* __restrict__ wb,
                                          const float* __restrict__ v,
                                          int lane, float& oa, float& ob) {
    const float4* a4 = reinterpret_cast<const float4*>(wa);
    const float4* b4 = reinterpret_cast<const float4*>(wb);
    const float4* v4 = reinterpret_cast<const float4*>(v);
    float sa = 0.f, sb = 0.f;
#pragma unroll
    for (int it = 0; it < 4; ++it) {
        const float4 x = a4[lane + it * 64];
        const float4 y = b4[lane + it * 64];
        const float4 u = v4[lane + it * 64];
        sa += x.x * u.x + x.y * u.y + x.z * u.z + x.w * u.w;
        sb += y.x * u.x + y.y * u.y + y.z * u.z + y.w * u.w;
    }
    oa = sa; ob = sb;
}

__device__ __forceinline__ void msmerge(float& m, float& s, float m2, float s2) {
    const float M = fmaxf(m, m2);
    s = s * expf(m - M) + s2 * expf(m2 - M);
    m = M;
}

// Two-level grid barrier, relaxed atomics only.
__device__ __forceinline__ void gbar(unsigned* bar, int slot) {
    __syncthreads();
    if (threadIdx.x == 0) {
        const int b = blockIdx.x, g = b >> 4;
        unsigned* leaf = bar + (slot * NGRP + g) * 16;
        unsigned* root = bar + BAR_ROOT + slot * 16;
        unsigned* rel  = bar + BAR_REL + g * 16;
        __hip_atomic_fetch_add(leaf, 1u, __ATOMIC_RELAXED, __HIP_MEMORY_SCOPE_AGENT);
        if ((b & 15) == 0) {
            while (uget(leaf) < 16u) __builtin_amdgcn_s_sleep(1);
            __hip_atomic_fetch_add(root, 1u, __ATOMIC_RELAXED, __HIP_MEMORY_SCOPE_AGENT);
            while (uget(root) < (unsigned)NGRP) __builtin_amdgcn_s_sleep(2);
            __hip_atomic_store(rel, (unsigned)(slot + 1), __ATOMIC_RELAXED,
                               __HIP_MEMORY_SCOPE_AGENT);
        } else {
            while (uget(rel) < (unsigned)(slot + 1)) __builtin_amdgcn_s_sleep(2);
        }
    }
    __syncthreads();
}

__global__ __launch_bounds__(NT, 8) void mega(
        const long long* __restrict__ idx_p,
        const float* __restrict__ hid,
        const float* __restrict__ enc,
        const float* __restrict__ emb,
        const float* __restrict__ attn_W,
        const float* __restrict__ attn_b,
        const float* __restrict__ comb_W,
        const float* __restrict__ comb_b,
        const float* __restrict__ w_ih,
        const float* __restrict__ w_hh,
        const float* __restrict__ b_ih,
        const float* __restrict__ b_hh,
        const float* __restrict__ out_W,
        const float* __restrict__ out_b,
        float* __restrict__ ws,
        float* __restrict__ out) {
    __shared__ __align__(16) float lds_a[H];    // hid -> x -> h_new
    __shared__ __align__(16) float lds_b[H];    // emb_row -> attn_applied
    __shared__ float lds_c[64];                 // wls / reduce slots
    __shared__ float lds_log[64];               // this block's out-proj logits

    unsigned* bar = reinterpret_cast<unsigned*>(ws);
    const int tid  = threadIdx.x;
    const int lane = tid & 63, wid = tid >> 6;  // 8 waves
    const int b    = blockIdx.x;
    const int idx  = (int)idx_p[0];

    // ===== S1: gh + comb-emb-half + attn-logit halves (all CUs uniform) ====
    for (int i = tid; i < H; i += NT) {
        lds_a[i] = hid[i];
        lds_b[i] = emb[(size_t)idx * H + i];
    }
    __syncthreads();
    if (wid < 3) {                         // gh rows: r = wid*NB + b
        const int r = wid * NB + b;
        float acc = wsum(dot1024(w_hh + (size_t)r * H, lds_a, lane));
        if (lane == 0) gput(ws + OFF_GH + r, acc + b_hh[r]);
    } else if (wid == 3) {                 // comb emb-half row b
        float acc = wsum(dot1024(comb_W + (size_t)b * (2 * H), lds_b, lane));
        if (lane == 0) gput(ws + OFF_CP + b, acc);
    } else if (wid == 4 && b < 128) {      // attn logit halves
        if (b < 64) {
            float acc = wsum(dot1024(attn_W + (size_t)b * (2 * H), lds_b, lane));
            if (lane == 0) gput(ws + OFF_WE + b, acc);
        } else {
            const int l = b - 64;
            float acc = wsum(dot1024(attn_W + (size_t)l * (2 * H) + H, lds_a, lane));
            if (lane == 0) gput(ws + OFF_WH + l, acc);
        }
    }
    gbar(bar, 0);

    // ===== S2: softmax + attn_applied + comb-attn-half -> x (1 block/CU) ===
    if ((b & 3) == 0) {
        const int bb = b >> 2;             // 0..255
        if (wid == 0) {
            const float lg = gget(ws + OFF_WE + lane) + gget(ws + OFF_WH + lane)
                           + attn_b[lane];
            const float m = wmax(lg);
            const float e = expf(lg - m);
            const float s = wsum(e);
            const float wl = e / s;
            lds_c[lane] = wl;
            if (b == 0) out[V + H + lane] = wl;
        }
        __syncthreads();
        if (tid < 256) {
            const float4* e4 = reinterpret_cast<const float4*>(enc);
            float4 a4 = {0.f, 0.f, 0.f, 0.f};
#pragma unroll 8
            for (int l = 0; l < L; ++l) {
                const float wl = lds_c[l];
                const float4 v = e4[l * 256 + tid];
                a4.x += wl * v.x; a4.y += wl * v.y;
                a4.z += wl * v.z; a4.w += wl * v.w;
            }
            reinterpret_cast<float4*>(lds_b)[tid] = a4;
        }
        __syncthreads();
        if (wid < 4) {
            const int r = bb * 4 + wid;    // 1024 rows total
            float acc = wsum(dot1024(comb_W + (size_t)r * (2 * H) + H, lds_b, lane));
            if (lane == 0)
                gput(ws + OFF_X + r,
                     fmaxf(acc + gget(ws + OFF_CP + r) + comb_b[r], 0.f));
        }
    }
    gbar(bar, 1);

    // ===== S3: gi (3 dots) + gates for t = b (one wave/block, all CUs) =====
    if (wid == 0) {
        for (int i = lane; i < H; i += 64) lds_a[i] = gget(ws + OFF_X + i);
        const int t = b;
        const float* r0 = w_ih + (size_t)t * H;
        const float* r1 = w_ih + (size_t)(H + t) * H;
        const float* r2 = w_ih + (size_t)(2 * H + t) * H;
        float g0, g1, g2;
        {   // 12 global loads in flight, 3 independent reduces
            float a, bq;
            dot1024x2(r0, r1, lds_a, lane, a, bq);
            g2 = dot1024(r2, lds_a, lane);
            g0 = wsum(a); g1 = wsum(bq); g2 = wsum(g2);
        }
        if (lane == 0) {
            const float ir = g0 + b_ih[t];
            const float iz = g1 + b_ih[H + t];
            const float in_ = g2 + b_ih[2 * H + t];
            const float hr = gget(ws + OFF_GH + t);
            const float hz = gget(ws + OFF_GH + H + t);
            const float hn = gget(ws + OFF_GH + 2 * H + t);
            const float r = 1.f / (1.f + expf(-(ir + hr)));
            const float z = 1.f / (1.f + expf(-(iz + hz)));
            const float n = tanhf(in_ + r * hn);
            const float hnew = (1.f - z) * n + z * hid[t];
            out[V + t] = hnew;
            gput(ws + OFF_HN + t, hnew);
        }
    }
    gbar(bar, 2);

    // ===== S4: out-proj GEMV, 50 rows/block, 2-row ILP per wave ============
    for (int i = tid; i < H; i += NT) lds_a[i] = gget(ws + OFF_HN + i);
    __syncthreads();
    const int row0  = b * RPB;
    const int nrows = (row0 < V) ? min(RPB, V - row0) : 0;
#pragma unroll
    for (int j = 0; j < 3; ++j) {
        const int k0 = wid + j * 16, k1 = k0 + 8;
        const int r0 = row0 + k0, r1 = row0 + k1;
        const bool v0 = r0 < V, v1 = r1 < V;
        const float* p0 = out_W + (size_t)(v0 ? r0 : 0) * H;
        const float* p1 = out_W + (size_t)(v1 ? r1 : 0) * H;
        float a0, a1;
        dot1024x2(p0, p1, lds_a, lane, a0, a1);
        a0 = wsum(a0); a1 = wsum(a1);
        if (lane == 0) {
            if (v0) lds_log[k0] = a0 + out_b[r0];
            if (v1) lds_log[k1] = a1 + out_b[r1];
        }
    }
    if (wid < 2) {                         // tail rows 48, 49
        const int k = 48 + wid, r = row0 + k;
        if (r < V) {
            float a = wsum(dot1024(out_W + (size_t)r * H, lds_a, lane));
            if (lane == 0) lds_log[k] = a + out_b[r];
        }
    }
    __syncthreads();
    if (wid == 0) {                        // block (m,s) partial (nrows <= 50)
        const float v = (lane < nrows) ? lds_log[lane] : -INFINITY;
        const float m = wmax(v);
        const float e = (lane < nrows) ? expf(v - m) : 0.f;
        const float s = wsum(e);
        if (lane == 0) {
            gput(ws + OFF_PAIR + 2 * b, m);
            gput(ws + OFF_PAIR + 2 * b + 1, s);
        }
    }
    gbar(bar, 3);

    // ===== S5: redundant global LSE + final write ===========================
    float m = -INFINITY, s = 0.f;
    for (int i = tid; i < NB; i += NT) {   // 2 iterations
        const float mi = gget(ws + OFF_PAIR + 2 * i);
        const float si = gget(ws + OFF_PAIR + 2 * i + 1);
        if (si > 0.f) msmerge(m, s, mi, si);
    }
#pragma unroll
    for (int off = 32; off > 0; off >>= 1) {
        const float mo = __shfl_xor(m, off);
        const float so = __shfl_xor(s, off);
        if (so > 0.f) msmerge(m, s, mo, so);
    }
    if (lane == 0) { lds_c[wid] = m; lds_c[8 + wid] = s; }
    __syncthreads();
    if (tid == 0) {
        float M = lds_c[0], S = lds_c[8];
        for (int i = 1; i < 8; ++i)
            if (lds_c[8 + i] > 0.f) msmerge(M, S, lds_c[i], lds_c[8 + i]);
        lds_c[16] = M;
        lds_c[17] = logf(S);
    }
    __syncthreads();
    const float MM = lds_c[16], LS = lds_c[17];
    if (tid < nrows) out[row0 + tid] = lds_log[tid] - MM - LS;
}

extern "C" void kernel_launch(void* const* d_in, const int* in_sizes, int n_in,
                              void* d_out, int out_size, void* d_ws, size_t ws_size,
                              hipStream_t stream) {
    const long long* idx  = (const long long*)d_in[0];
    const float* hid    = (const float*)d_in[1];
    const float* enc    = (const float*)d_in[2];
    const float* emb    = (const float*)d_in[3];
    const float* attn_W = (const float*)d_in[4];
    const float* attn_b = (const float*)d_in[5];
    const float* comb_W = (const float*)d_in[6];
    const float* comb_b = (const float*)d_in[7];
    const float* w_ih   = (const float*)d_in[8];
    const float* w_hh   = (const float*)d_in[9];
    const float* b_ih   = (const float*)d_in[10];
    const float* b_hh   = (const float*)d_in[11];
    const float* out_W  = (const float*)d_in[12];
    const float* out_b  = (const float*)d_in[13];
    float* out = (float*)d_out;
    float* ws  = (float*)d_ws;

    hipMemsetAsync(d_ws, 0, BAR_UINTS * sizeof(unsigned), stream);
    mega<<<NB, NT, 0, stream>>>(idx, hid, enc, emb, attn_W, attn_b,
                                comb_W, comb_b, w_ih, w_hh, b_ih, b_hh,
                                out_W, out_b, ws, out);
}

// Round 6
// 88.197 us; speedup vs baseline: 1.0217x; 1.0217x over previous
//
#include <hip/hip_runtime.h>
#include <math.h>

constexpr int H = 1024;
constexpr int V = 50257;
constexpr int L = 64;

constexpr int NB   = 1024;              // 4 blocks/CU
constexpr int NT   = 512;               // 8 waves/block -> 32 waves/CU
constexpr int NGRP = 64;                // 16 blocks per barrier group
constexpr int RPB  = 50;                // ceil(V/NB) rows per block in S4

// ---- barrier region (uints, 64B-strided, zeroed per call) -----------------
constexpr int BAR_ROOT  = 4 * NGRP * 16;        // leaf: (slot*NGRP+g)*16
constexpr int BAR_REL   = BAR_ROOT + 4 * 16;
constexpr int BAR_UINTS = BAR_REL + NGRP * 16;  // 5184 uints

// ---- ws float offsets: 1KB-aligned, 256-float guards between stages -------
// (guards prevent a cached consumer read of stage buffer A from pulling a
//  not-yet-written line of stage buffer B into an XCD L2)
constexpr int OFF_WE   = 5376;                  // 64   attn logits, emb half
constexpr int OFF_WH   = OFF_WE + 256;          // 64   attn logits, hid half
constexpr int OFF_GH   = OFF_WH + 256;          // 3072 gh
constexpr int OFF_CP   = OFF_GH + 3 * H + 256;  // 1024 comb emb-half partial
constexpr int OFF_X    = OFF_CP + H + 256;      // 1024 x = relu(comb)
constexpr int OFF_HN   = OFF_X + H + 256;       // 1024 h_new
constexpr int OFF_PAIR = OFF_HN + H + 256;      // 2*NB (m,s) partials

// Producer writes: through to the coherence point (cross-XCD visible).
__device__ __forceinline__ void gput(float* p, float v) {
    __hip_atomic_store(p, v, __ATOMIC_RELAXED, __HIP_MEMORY_SCOPE_AGENT);
}
// Barrier counters only (polled, must bypass caches).
__device__ __forceinline__ unsigned uget(const unsigned* p) {
    return __hip_atomic_load(p, __ATOMIC_RELAXED, __HIP_MEMORY_SCOPE_AGENT);
}

__device__ __forceinline__ float wsum(float v) {
#pragma unroll
    for (int off = 32; off > 0; off >>= 1) v += __shfl_xor(v, off);
    return v;
}
__device__ __forceinline__ float wmax(float v) {
#pragma unroll
    for (int off = 32; off > 0; off >>= 1) v = fmaxf(v, __shfl_xor(v, off));
    return v;
}

__device__ __forceinline__ float dot1024(const float* __restrict__ w,
                                         const float* __restrict__ v,
                                         int lane) {
    const float4* w4 = reinterpret_cast<const float4*>(w);
    const float4* v4 = reinterpret_cast<const float4*>(v);
    float acc = 0.f;
#pragma unroll
    for (int it = 0; it < 4; ++it) {
        const float4 a = w4[lane + it * 64];
        const float4 b = v4[lane + it * 64];
        acc += a.x * b.x + a.y * b.y + a.z * b.z + a.w * b.w;
    }
    return acc;
}

// Two rows at once: 8 global dwordx4 in flight before any reduce.
__device__ __forceinline__ void dot1024x2(const float* __restrict__ wa,
                                          const float* __restrict__ wb,
                                          const float* __restrict__ v,
                                          int lane, float& oa, float& ob) {
    const float4* a4 = reinterpret_cast<const float4*>(wa);
    const float4* b4 = reinterpret_cast<const float4*>(wb);
    const float4* v4 = reinterpret_cast<const float4*>(v);
    float sa = 0.f, sb = 0.f;
#pragma unroll
    for (int it = 0; it < 4; ++it) {
        const float4 x = a4[lane + it * 64];
        const float4 y = b4[lane + it * 64];
        const float4 u = v4[lane + it * 64];
        sa += x.x * u.x + x.y * u.y + x.z * u.z + x.w * u.w;
        sb += y.x * u.x + y.y * u.y + y.z * u.z + y.w * u.w;
    }
    oa = sa; ob = sb;
}

__device__ __forceinline__ void msmerge(float& m, float& s, float m2, float s2) {
    const float M = fmaxf(m, m2);
    s = s * expf(m - M) + s2 * expf(m2 - M);
    m = M;
}

// Two-level grid barrier, relaxed atomics only (1 polling thread per block).
__device__ __forceinline__ void gbar(unsigned* bar, int slot) {
    __syncthreads();
    if (threadIdx.x == 0) {
        const int b = blockIdx.x, g = b >> 4;
        unsigned* leaf = bar + (slot * NGRP + g) * 16;
        unsigned* root = bar + BAR_ROOT + slot * 16;
        unsigned* rel  = bar + BAR_REL + g * 16;
        __hip_atomic_fetch_add(leaf, 1u, __ATOMIC_RELAXED, __HIP_MEMORY_SCOPE_AGENT);
        if ((b & 15) == 0) {
            while (uget(leaf) < 16u) __builtin_amdgcn_s_sleep(1);
            __hip_atomic_fetch_add(root, 1u, __ATOMIC_RELAXED, __HIP_MEMORY_SCOPE_AGENT);
            while (uget(root) < (unsigned)NGRP) __builtin_amdgcn_s_sleep(2);
            __hip_atomic_store(rel, (unsigned)(slot + 1), __ATOMIC_RELAXED,
                               __HIP_MEMORY_SCOPE_AGENT);
        } else {
            while (uget(rel) < (unsigned)(slot + 1)) __builtin_amdgcn_s_sleep(2);
        }
    }
    __syncthreads();
}

__global__ __launch_bounds__(NT, 8) void mega(
        const long long* __restrict__ idx_p,
        const float* __restrict__ hid,
        const float* __restrict__ enc,
        const float* __restrict__ emb,
        const float* __restrict__ attn_W,
        const float* __restrict__ attn_b,
        const float* __restrict__ comb_W,
        const float* __restrict__ comb_b,
        const float* __restrict__ w_ih,
        const float* __restrict__ w_hh,
        const float* __restrict__ b_ih,
        const float* __restrict__ b_hh,
        const float* __restrict__ out_W,
        const float* __restrict__ out_b,
        float* __restrict__ ws,
        float* __restrict__ out) {
    __shared__ __align__(16) float lds_a[H];    // hid -> x -> h_new
    __shared__ __align__(16) float lds_b[H];    // emb_row -> attn_applied
    __shared__ float lds_c[64];                 // wls / reduce slots
    __shared__ float lds_log[64];               // this block's out-proj logits

    unsigned* bar = reinterpret_cast<unsigned*>(ws);
    const int tid  = threadIdx.x;
    const int lane = tid & 63, wid = tid >> 6;  // 8 waves
    const int b    = blockIdx.x;
    const int idx  = (int)idx_p[0];

    // ===== S1: gh + comb-emb-half + attn-logit halves (all CUs uniform) ====
    for (int i = tid; i < H; i += NT) {
        lds_a[i] = hid[i];
        lds_b[i] = emb[(size_t)idx * H + i];
    }
    __syncthreads();
    if (wid < 3) {                         // gh rows: r = wid*NB + b
        const int r = wid * NB + b;
        float acc = wsum(dot1024(w_hh + (size_t)r * H, lds_a, lane));
        if (lane == 0) gput(ws + OFF_GH + r, acc + b_hh[r]);
    } else if (wid == 3) {                 // comb emb-half row b
        float acc = wsum(dot1024(comb_W + (size_t)b * (2 * H), lds_b, lane));
        if (lane == 0) gput(ws + OFF_CP + b, acc);
    } else if (wid == 4 && b < 128) {      // attn logit halves
        if (b < 64) {
            float acc = wsum(dot1024(attn_W + (size_t)b * (2 * H), lds_b, lane));
            if (lane == 0) gput(ws + OFF_WE + b, acc);
        } else {
            const int l = b - 64;
            float acc = wsum(dot1024(attn_W + (size_t)l * (2 * H) + H, lds_a, lane));
            if (lane == 0) gput(ws + OFF_WH + l, acc);
        }
    }
    gbar(bar, 0);

    // ===== S2: softmax + attn_applied + comb-attn-half -> x (1 block/CU) ===
    if ((b & 3) == 0) {
        const int bb = b >> 2;             // 0..255
        if (wid == 0) {                    // cached loads: L2 serves per-XCD
            const float lg = ws[OFF_WE + lane] + ws[OFF_WH + lane] + attn_b[lane];
            const float m = wmax(lg);
            const float e = expf(lg - m);
            const float s = wsum(e);
            const float wl = e / s;
            lds_c[lane] = wl;
            if (b == 0) out[V + H + lane] = wl;
        }
        __syncthreads();
        if (tid < 256) {
            const float4* e4 = reinterpret_cast<const float4*>(enc);
            float4 a4 = {0.f, 0.f, 0.f, 0.f};
#pragma unroll 8
            for (int l = 0; l < L; ++l) {
                const float wl = lds_c[l];
                const float4 v = e4[l * 256 + tid];
                a4.x += wl * v.x; a4.y += wl * v.y;
                a4.z += wl * v.z; a4.w += wl * v.w;
            }
            reinterpret_cast<float4*>(lds_b)[tid] = a4;
        }
        __syncthreads();
        if (wid < 4) {
            const int r = bb * 4 + wid;    // 1024 rows total
            float acc = wsum(dot1024(comb_W + (size_t)r * (2 * H) + H, lds_b, lane));
            if (lane == 0)
                gput(ws + OFF_X + r,
                     fmaxf(acc + ws[OFF_CP + r] + comb_b[r], 0.f));
        }
    }
    gbar(bar, 1);

    // ===== S3: gi (3 dots) + gates for t = b (one dot-wave/block) ==========
    for (int i = tid; i < H; i += NT) lds_a[i] = ws[OFF_X + i];  // cached
    __syncthreads();
    if (wid == 0) {
        const int t = b;
        const float* r0 = w_ih + (size_t)t * H;
        const float* r1 = w_ih + (size_t)(H + t) * H;
        const float* r2 = w_ih + (size_t)(2 * H + t) * H;
        float g0, g1, g2;
        {
            float a, bq;
            dot1024x2(r0, r1, lds_a, lane, a, bq);
            g2 = dot1024(r2, lds_a, lane);
            g0 = wsum(a); g1 = wsum(bq); g2 = wsum(g2);
        }
        if (lane == 0) {
            const float ir = g0 + b_ih[t];
            const float iz = g1 + b_ih[H + t];
            const float in_ = g2 + b_ih[2 * H + t];
            const float hr = ws[OFF_GH + t];
            const float hz = ws[OFF_GH + H + t];
            const float hn = ws[OFF_GH + 2 * H + t];
            const float r = 1.f / (1.f + expf(-(ir + hr)));
            const float z = 1.f / (1.f + expf(-(iz + hz)));
            const float n = tanhf(in_ + r * hn);
            const float hnew = (1.f - z) * n + z * hid[t];
            out[V + t] = hnew;
            gput(ws + OFF_HN + t, hnew);
        }
    }
    gbar(bar, 2);

    // ===== S4: out-proj GEMV, 50 rows/block, 2-row ILP per wave ============
    for (int i = tid; i < H; i += NT) lds_a[i] = ws[OFF_HN + i];  // cached
    __syncthreads();
    const int row0  = b * RPB;
    const int nrows = (row0 < V) ? min(RPB, V - row0) : 0;
#pragma unroll
    for (int j = 0; j < 3; ++j) {
        const int k0 = wid + j * 16, k1 = k0 + 8;
        const int r0 = row0 + k0, r1 = row0 + k1;
        const bool v0 = r0 < V, v1 = r1 < V;
        const float* p0 = out_W + (size_t)(v0 ? r0 : 0) * H;
        const float* p1 = out_W + (size_t)(v1 ? r1 : 0) * H;
        float a0, a1;
        dot1024x2(p0, p1, lds_a, lane, a0, a1);
        a0 = wsum(a0); a1 = wsum(a1);
        if (lane == 0) {
            if (v0) lds_log[k0] = a0 + out_b[r0];
            if (v1) lds_log[k1] = a1 + out_b[r1];
        }
    }
    if (wid < 2) {                         // tail rows 48, 49
        const int k = 48 + wid, r = row0 + k;
        if (r < V) {
            float a = wsum(dot1024(out_W + (size_t)r * H, lds_a, lane));
            if (lane == 0) lds_log[k] = a + out_b[r];
        }
    }
    __syncthreads();
    if (wid == 0) {                        // block (m,s) partial (nrows <= 50)
        const float v = (lane < nrows) ? lds_log[lane] : -INFINITY;
        const float m = wmax(v);
        const float e = (lane < nrows) ? expf(v - m) : 0.f;
        const float s = wsum(e);
        if (lane == 0) {
            gput(ws + OFF_PAIR + 2 * b, m);
            gput(ws + OFF_PAIR + 2 * b + 1, s);
        }
    }
    gbar(bar, 3);

    // ===== S5: redundant global LSE (cached reads) + final write ===========
    float m = -INFINITY, s = 0.f;
    for (int i = tid; i < NB; i += NT) {   // 2 iterations, plain loads
        const float mi = ws[OFF_PAIR + 2 * i];
        const float si = ws[OFF_PAIR + 2 * i + 1];
        if (si > 0.f) msmerge(m, s, mi, si);
    }
#pragma unroll
    for (int off = 32; off > 0; off >>= 1) {
        const float mo = __shfl_xor(m, off);
        const float so = __shfl_xor(s, off);
        if (so > 0.f) msmerge(m, s, mo, so);
    }
    if (lane == 0) { lds_c[wid] = m; lds_c[8 + wid] = s; }
    __syncthreads();
    if (tid == 0) {
        float M = lds_c[0], S = lds_c[8];
        for (int i = 1; i < 8; ++i)
            if (lds_c[8 + i] > 0.f) msmerge(M, S, lds_c[i], lds_c[8 + i]);
        lds_c[16] = M;
        lds_c[17] = logf(S);
    }
    __syncthreads();
    const float MM = lds_c[16], LS = lds_c[17];
    if (tid < nrows) out[row0 + tid] = lds_log[tid] - MM - LS;
}

extern "C" void kernel_launch(void* const* d_in, const int* in_sizes, int n_in,
                              void* d_out, int out_size, void* d_ws, size_t ws_size,
                              hipStream_t stream) {
    const long long* idx  = (const long long*)d_in[0];
    const float* hid    = (const float*)d_in[1];
    const float* enc    = (const float*)d_in[2];
    const float* emb    = (const float*)d_in[3];
    const float* attn_W = (const float*)d_in[4];
    const float* attn_b = (const float*)d_in[5];
    const float* comb_W = (const float*)d_in[6];
    const float* comb_b = (const float*)d_in[7];
    const float* w_ih   = (const float*)d_in[8];
    const float* w_hh   = (const float*)d_in[9];
    const float* b_ih   = (const float*)d_in[10];
    const float* b_hh   = (const float*)d_in[11];
    const float* out_W  = (const float*)d_in[12];
    const float* out_b  = (const float*)d_in[13];
    float* out = (float*)d_out;
    float* ws  = (float*)d_ws;

    hipMemsetAsync(d_ws, 0, BAR_UINTS * sizeof(unsigned), stream);
    mega<<<NB, NT, 0, stream>>>(idx, hid, enc, emb, attn_W, attn_b,
                                comb_W, comb_b, w_ih, w_hh, b_ih, b_hh,
                                out_W, out_b, ws, out);
}

// Round 7
// 68.826 us; speedup vs baseline: 1.3093x; 1.2815x over previous
//
#include <hip/hip_runtime.h>
#include <math.h>

constexpr int H = 1024;
constexpr int V = 50257;
constexpr int L = 64;

constexpr int NBLK3 = (V + 15) / 16;   // 3142 out-proj blocks, 16 rows each

// ws float offsets
constexpr int OFF_X    = 0;            // 1024: x = relu(comb)
constexpr int OFF_LOG  = 1024;         // V logits
constexpr int OFF_PAIR = 1024 + V;     // 2*NBLK3 (m,s) pairs

__device__ __forceinline__ float wsum(float v) {
#pragma unroll
    for (int off = 32; off > 0; off >>= 1) v += __shfl_xor(v, off);
    return v;
}
__device__ __forceinline__ float wmax(float v) {
#pragma unroll
    for (int off = 32; off > 0; off >>= 1) v = fmaxf(v, __shfl_xor(v, off));
    return v;
}

__device__ __forceinline__ float dot4(float4 a, float4 b) {
    return a.x * b.x + a.y * b.y + a.z * b.z + a.w * b.w;
}

__device__ __forceinline__ float dotN(const float* __restrict__ w,
                                      const float* __restrict__ v,
                                      int lane, int n4) { // n4 = N/256
    const float4* w4 = reinterpret_cast<const float4*>(w);
    const float4* v4 = reinterpret_cast<const float4*>(v);
    float acc = 0.f;
    for (int it = 0; it < n4; ++it)
        acc += dot4(w4[lane + it * 64], v4[lane + it * 64]);
    return acc;
}

// 4 rows at once: 16 global dwordx4 in flight before any reduce.
__device__ __forceinline__ void dot1024x4(const float* __restrict__ w0,
                                          const float* __restrict__ w1,
                                          const float* __restrict__ w2,
                                          const float* __restrict__ w3,
                                          const float* __restrict__ v,
                                          int lane, float* o) {
    const float4* a4 = reinterpret_cast<const float4*>(w0);
    const float4* b4 = reinterpret_cast<const float4*>(w1);
    const float4* c4 = reinterpret_cast<const float4*>(w2);
    const float4* d4 = reinterpret_cast<const float4*>(w3);
    const float4* v4 = reinterpret_cast<const float4*>(v);
    float s0 = 0.f, s1 = 0.f, s2 = 0.f, s3 = 0.f;
#pragma unroll
    for (int it = 0; it < 4; ++it) {
        const float4 u = v4[lane + it * 64];
        s0 += dot4(a4[lane + it * 64], u);
        s1 += dot4(b4[lane + it * 64], u);
        s2 += dot4(c4[lane + it * 64], u);
        s3 += dot4(d4[lane + it * 64], u);
    }
    o[0] = s0; o[1] = s1; o[2] = s2; o[3] = s3;
}

__device__ __forceinline__ void msmerge(float& m, float& s, float m2, float s2) {
    const float M = fmaxf(m, m2);
    s = s * expf(m - M) + s2 * expf(m2 - M);
    m = M;
}

// ==== K1: attn logits (redundant/block) + softmax + attn_applied + comb ====
__global__ __launch_bounds__(512) void k1_front(
        const long long* __restrict__ idx_p,
        const float* __restrict__ hid,
        const float* __restrict__ enc,
        const float* __restrict__ emb,
        const float* __restrict__ attn_W,
        const float* __restrict__ attn_b,
        const float* __restrict__ comb_W,
        const float* __restrict__ comb_b,
        float* __restrict__ ws,
        float* __restrict__ out) {
    __shared__ __align__(16) float ecat[2 * H];   // [emb_row | hid] -> [emb | attn]
    __shared__ __align__(16) float part[H];       // half-split partial
    __shared__ float slog[L];
    __shared__ float wls[L];
    const int tid = threadIdx.x, lane = tid & 63, wid = tid >> 6;
    const int b = blockIdx.x;                      // 128 blocks
    const int idx = (int)idx_p[0];

    for (int i = tid; i < H; i += 512) {
        ecat[i]     = emb[(size_t)idx * H + i];
        ecat[H + i] = hid[i];
    }
    __syncthreads();
    // attn logits: 8 rows per wave (all 64 rows per block, redundant per block)
    for (int r = wid; r < L; r += 8) {
        float acc = wsum(dotN(attn_W + (size_t)r * (2 * H), ecat, lane, 8));
        if (lane == 0) slog[r] = acc + attn_b[r];
    }
    __syncthreads();
    if (wid == 0) {   // softmax entirely in wave 0 (lane l owns logit l)
        const float lg = slog[lane];
        const float m = wmax(lg);
        const float e = expf(lg - m);
        const float s = wsum(e);
        wls[lane] = e / s;
        if (b == 0) out[V + H + lane] = e / s;
    }
    __syncthreads();
    // attn_applied: 512 threads, each float4-chunk (tid&255), half of L (tid>>8)
    {
        const float4* e4 = reinterpret_cast<const float4*>(enc);
        const int chunk = tid & 255, half = tid >> 8;
        float4 a4 = {0.f, 0.f, 0.f, 0.f};
#pragma unroll 8
        for (int l = half * 32; l < half * 32 + 32; ++l) {
            const float wl = wls[l];
            const float4 v = e4[l * 256 + chunk];
            a4.x += wl * v.x; a4.y += wl * v.y; a4.z += wl * v.z; a4.w += wl * v.w;
        }
        if (half == 1) reinterpret_cast<float4*>(part)[chunk] = a4;
        __syncthreads();
        if (half == 0) {
            const float4 p = reinterpret_cast<const float4*>(part)[chunk];
            a4.x += p.x; a4.y += p.y; a4.z += p.z; a4.w += p.w;
            reinterpret_cast<float4*>(ecat + H)[chunk] = a4;  // xcat = [emb|attn]
        }
    }
    __syncthreads();
    // comb: 8 rows per block (1024 rows over 128 blocks), one per wave
    {
        const int r = b * 8 + wid;
        float acc = wsum(dotN(comb_W + (size_t)r * (2 * H), ecat, lane, 8));
        if (lane == 0) ws[OFF_X + r] = fmaxf(acc + comb_b[r], 0.f);
    }
}

// ==== K2: gi + gh + gates -> h_new (block b owns t in [4b,4b+4)) ===========
__global__ __launch_bounds__(512) void k2_gru(
        const float* __restrict__ w_ih,
        const float* __restrict__ w_hh,
        const float* __restrict__ b_ih,
        const float* __restrict__ b_hh,
        const float* __restrict__ hid,
        const float* __restrict__ ws,
        float* __restrict__ out) {
    __shared__ __align__(16) float sx[H];
    __shared__ __align__(16) float sh[H];
    __shared__ float gr[24];
    const int tid = threadIdx.x, lane = tid & 63, wid = tid >> 6;
    const int t0 = blockIdx.x * 4;                 // 256 blocks
    for (int i = tid; i < H; i += 512) {
        sx[i] = ws[OFF_X + i];
        sh[i] = hid[i];
    }
    __syncthreads();
#pragma unroll
    for (int q = 0; q < 3; ++q) {                  // rows k = wid, wid+8, wid+16
        const int k = wid + q * 8;
        const int kk = (k < 12) ? k : k - 12;
        const int g = kk >> 2, j = kk & 3;
        const int row = g * H + t0 + j;
        float acc;
        if (k < 12) acc = wsum(dotN(w_ih + (size_t)row * H, sx, lane, 4)) + b_ih[row];
        else        acc = wsum(dotN(w_hh + (size_t)row * H, sh, lane, 4)) + b_hh[row];
        if (lane == 0) gr[k] = acc;
    }
    __syncthreads();
    if (tid < 4) {
        const int j = tid;
        const float ir = gr[j],      iz = gr[4 + j],  in_ = gr[8 + j];
        const float hr = gr[12 + j], hz = gr[16 + j], hn  = gr[20 + j];
        const float r = 1.f / (1.f + expf(-(ir + hr)));
        const float z = 1.f / (1.f + expf(-(iz + hz)));
        const float n = tanhf(in_ + r * hn);
        out[V + t0 + j] = (1.f - z) * n + z * sh[t0 + j];
    }
}

// ==== K3: out-proj GEMV, 16 rows/block, 4-row ILP per wave + (m,s) pair ====
__global__ __launch_bounds__(256, 4) void k3_outproj(
        const float* __restrict__ out_W,
        const float* __restrict__ out_b,
        const float* __restrict__ hnew,    // = out + V
        float* __restrict__ ws) {
    __shared__ __align__(16) float shn[H];
    __shared__ float srow[16];
    const int tid = threadIdx.x, lane = tid & 63, wid = tid >> 6;  // 4 waves
    for (int i = tid; i < H; i += 256) shn[i] = hnew[i];
    __syncthreads();
    const int row0 = blockIdx.x * 16 + wid * 4;
    const int r0 = min(row0,     V - 1), r1 = min(row0 + 1, V - 1);
    const int r2 = min(row0 + 2, V - 1), r3 = min(row0 + 3, V - 1);
    float o[4];
    dot1024x4(out_W + (size_t)r0 * H, out_W + (size_t)r1 * H,
              out_W + (size_t)r2 * H, out_W + (size_t)r3 * H, shn, lane, o);
#pragma unroll
    for (int j = 0; j < 4; ++j) {
        o[j] = wsum(o[j]);
        if (lane == 0) {
            const int r = row0 + j;
            srow[wid * 4 + j] = (r < V) ? (o[j] + out_b[r]) : -INFINITY;
            if (r < V) ws[OFF_LOG + r] = o[j] + out_b[r];
        }
    }
    __syncthreads();
    if (tid == 0) {
        float m = -INFINITY;
#pragma unroll
        for (int i = 0; i < 16; ++i) m = fmaxf(m, srow[i]);
        float s = 0.f;
#pragma unroll
        for (int i = 0; i < 16; ++i)
            if (srow[i] > -INFINITY) s += expf(srow[i] - m);
        ws[OFF_PAIR + 2 * blockIdx.x] = m;
        ws[OFF_PAIR + 2 * blockIdx.x + 1] = s;
    }
}

// ==== K4: redundant (m,s) combine + log-softmax write ======================
__global__ __launch_bounds__(256) void k4_write(const float* __restrict__ ws,
                                                float* __restrict__ out) {
    const int tid = threadIdx.x, lane = tid & 63, wid = tid >> 6;
    float m = -INFINITY, s = 0.f;
    for (int i = tid; i < NBLK3; i += 256) {
        const float mi = ws[OFF_PAIR + 2 * i];
        const float si = ws[OFF_PAIR + 2 * i + 1];
        if (si > 0.f) msmerge(m, s, mi, si);
    }
#pragma unroll
    for (int off = 32; off > 0; off >>= 1) {
        const float mo = __shfl_xor(m, off);
        const float so = __shfl_xor(s, off);
        if (so > 0.f) msmerge(m, s, mo, so);
    }
    __shared__ float sm[4], ss[4], fin[2];
    if (lane == 0) { sm[wid] = m; ss[wid] = s; }
    __syncthreads();
    if (tid == 0) {
        float M = sm[0], S = ss[0];
        for (int i = 1; i < 4; ++i)
            if (ss[i] > 0.f) msmerge(M, S, sm[i], ss[i]);
        fin[0] = M;
        fin[1] = logf(S);
    }
    __syncthreads();
    const int i = blockIdx.x * 256 + tid;
    if (i < V) out[i] = ws[OFF_LOG + i] - fin[0] - fin[1];
}

extern "C" void kernel_launch(void* const* d_in, const int* in_sizes, int n_in,
                              void* d_out, int out_size, void* d_ws, size_t ws_size,
                              hipStream_t stream) {
    const long long* idx  = (const long long*)d_in[0];
    const float* hid    = (const float*)d_in[1];
    const float* enc    = (const float*)d_in[2];
    const float* emb    = (const float*)d_in[3];
    const float* attn_W = (const float*)d_in[4];
    const float* attn_b = (const float*)d_in[5];
    const float* comb_W = (const float*)d_in[6];
    const float* comb_b = (const float*)d_in[7];
    const float* w_ih   = (const float*)d_in[8];
    const float* w_hh   = (const float*)d_in[9];
    const float* b_ih   = (const float*)d_in[10];
    const float* b_hh   = (const float*)d_in[11];
    const float* out_W  = (const float*)d_in[12];
    const float* out_b  = (const float*)d_in[13];
    float* out = (float*)d_out;
    float* ws  = (float*)d_ws;

    k1_front<<<128, 512, 0, stream>>>(idx, hid, enc, emb, attn_W, attn_b,
                                      comb_W, comb_b, ws, out);
    k2_gru<<<256, 512, 0, stream>>>(w_ih, w_hh, b_ih, b_hh, hid, ws, out);
    k3_outproj<<<NBLK3, 256, 0, stream>>>(out_W, out_b, out + V, ws);
    k4_write<<<(V + 255) / 256, 256, 0, stream>>>(ws, out);
}

// Round 8
// 57.737 us; speedup vs baseline: 1.5607x; 1.1920x over previous
//
#include <hip/hip_runtime.h>
#include <math.h>

constexpr int H = 1024;
constexpr int V = 50257;
constexpr int L = 64;

constexpr int NBLKD = 1024;            // out-proj blocks (4/CU, one generation)
constexpr int RPB   = 50;              // rows per out-proj block (1024*50 >= V)

// ws float offsets
constexpr int OFF_ALOG = 0;            // 64 attention logits
constexpr int OFF_GH   = 64;           // 3072: gh = w_hh@h0 + b_hh
constexpr int OFF_X    = 64 + 3 * H;   // 1024: x = relu(comb)
constexpr int OFF_LOG  = OFF_X + H;    // V logits
constexpr int OFF_PAIR = OFF_LOG + V;  // 2*NBLKD (m,s) pairs

__device__ __forceinline__ float wsum(float v) {
#pragma unroll
    for (int off = 32; off > 0; off >>= 1) v += __shfl_xor(v, off);
    return v;
}
__device__ __forceinline__ float wmax(float v) {
#pragma unroll
    for (int off = 32; off > 0; off >>= 1) v = fmaxf(v, __shfl_xor(v, off));
    return v;
}

__device__ __forceinline__ float dot4(float4 a, float4 b) {
    return a.x * b.x + a.y * b.y + a.z * b.z + a.w * b.w;
}

__device__ __forceinline__ float dotN(const float* __restrict__ w,
                                      const float* __restrict__ v,
                                      int lane, int n4) { // n4 = N/256
    const float4* w4 = reinterpret_cast<const float4*>(w);
    const float4* v4 = reinterpret_cast<const float4*>(v);
    float acc = 0.f;
    for (int it = 0; it < n4; ++it)
        acc += dot4(w4[lane + it * 64], v4[lane + it * 64]);
    return acc;
}

__device__ __forceinline__ void msmerge(float& m, float& s, float m2, float s2) {
    const float M = fmaxf(m, m2);
    s = s * expf(m - M) + s2 * expf(m2 - M);
    m = M;
}

// ---- A: attention logits (blocks 0..63) || gh GEMV (blocks 64..831) -------
__global__ __launch_bounds__(256) void kA(const long long* __restrict__ idx_p,
                                          const float* __restrict__ hid,
                                          const float* __restrict__ emb,
                                          const float* __restrict__ attn_W,
                                          const float* __restrict__ attn_b,
                                          const float* __restrict__ w_hh,
                                          const float* __restrict__ b_hh,
                                          float* __restrict__ ws) {
    const int tid = threadIdx.x;
    const int lane = tid & 63, wid = tid >> 6;
    if (blockIdx.x < 64) {
        const int l = blockIdx.x;
        const int idx = (int)idx_p[0];
        const float4* w4 = reinterpret_cast<const float4*>(attn_W + (size_t)l * (2 * H));
        const float4* e4 = reinterpret_cast<const float4*>(emb + (size_t)idx * H);
        const float4* h4 = reinterpret_cast<const float4*>(hid);
        float acc = dot4(w4[tid], e4[tid]) + dot4(w4[tid + 256], h4[tid]);
        acc = wsum(acc);
        __shared__ float sred[4];
        if (lane == 0) sred[wid] = acc;
        __syncthreads();
        if (tid == 0)
            ws[OFF_ALOG + l] = sred[0] + sred[1] + sred[2] + sred[3] + attn_b[l];
    } else {
        __shared__ __align__(16) float4 sv[256];
        sv[tid] = reinterpret_cast<const float4*>(hid)[tid];
        __syncthreads();
        const int row = (blockIdx.x - 64) * 4 + wid;  // 0..3071
        float acc = wsum(dotN(w_hh + (size_t)row * H,
                              reinterpret_cast<const float*>(sv), lane, 4));
        if (lane == 0) ws[OFF_GH + row] = acc + b_hh[row];
    }
}

// ---- B: softmax + attn_applied + xcat + comb GEMV (256 blocks) ------------
__global__ __launch_bounds__(256) void kB(const long long* __restrict__ idx_p,
                                          const float* __restrict__ emb,
                                          const float* __restrict__ enc,
                                          const float* __restrict__ comb_W,
                                          const float* __restrict__ comb_b,
                                          float* __restrict__ ws,
                                          float* __restrict__ out) {
    __shared__ float wls[L];
    __shared__ __align__(16) float4 sx[512];  // xcat: [embedded | attn_applied]
    const int tid = threadIdx.x;
    if (tid < L) {
        const float lg = ws[OFF_ALOG + tid];
        // wave 0 holds all 64 logits in its 64 lanes
        const float m = wmax(lg);
        const float e = expf(lg - m);
        const float s = wsum(e);
        wls[tid] = e / s;
        if (blockIdx.x == 0) out[V + H + tid] = e / s;
    }
    __syncthreads();
    const int idx = (int)idx_p[0];
    sx[tid] = reinterpret_cast<const float4*>(emb + (size_t)idx * H)[tid];
    {
        const float4* e4 = reinterpret_cast<const float4*>(enc);
        float4 a4 = {0.f, 0.f, 0.f, 0.f};
#pragma unroll 8
        for (int l = 0; l < L; ++l) {
            const float wl = wls[l];
            const float4 v = e4[l * 256 + tid];
            a4.x += wl * v.x; a4.y += wl * v.y;
            a4.z += wl * v.z; a4.w += wl * v.w;
        }
        sx[256 + tid] = a4;
    }
    __syncthreads();
    const int lane = tid & 63, wid = tid >> 6;
    const int row = blockIdx.x * 4 + wid;  // 0..1023
    float acc = wsum(dotN(comb_W + (size_t)row * (2 * H),
                          reinterpret_cast<const float*>(sx), lane, 8));
    if (lane == 0) ws[OFF_X + row] = fmaxf(acc + comb_b[row], 0.f);
}

// ---- C: gi GEMV + GRU gates fused (256 blocks x 768 threads) --------------
__global__ __launch_bounds__(768) void kC(const float* __restrict__ w_ih,
                                          const float* __restrict__ b_ih,
                                          const float* __restrict__ hid,
                                          float* __restrict__ ws,
                                          float* __restrict__ out) {
    __shared__ __align__(16) float4 sx4[256];  // x
    __shared__ float gi_s[12];
    const int tid = threadIdx.x;
    if (tid < 256) sx4[tid] = reinterpret_cast<const float4*>(ws + OFF_X)[tid];
    __syncthreads();
    const int lane = tid & 63, wid = tid >> 6;  // wid 0..11
    const int g = wid >> 2, i = wid & 3;
    const int row = g * H + blockIdx.x * 4 + i;
    float acc = wsum(dotN(w_ih + (size_t)row * H,
                          reinterpret_cast<const float*>(sx4), lane, 4));
    if (lane == 0) gi_s[wid] = acc + b_ih[row];
    __syncthreads();
    if (tid < 4) {
        const int t = blockIdx.x * 4 + tid;
        const float ir = gi_s[tid], iz = gi_s[4 + tid], in_ = gi_s[8 + tid];
        const float hr = ws[OFF_GH + t];
        const float hz = ws[OFF_GH + H + t];
        const float hn = ws[OFF_GH + 2 * H + t];
        const float r = 1.f / (1.f + expf(-(ir + hr)));
        const float z = 1.f / (1.f + expf(-(iz + hz)));
        const float n = tanhf(in_ + r * hn);
        out[V + t] = (1.f - z) * n + z * hid[t];
    }
}

// ---- D': out-proj GEMV. 1024 blocks x 512 thr, 50 contiguous rows/block ---
// One block generation per CU (zero churn); wave-per-row loop; VGPR<=64
// guarantees 8 waves/SIMD so ~32 outstanding dwordx4 loads per SIMD.
__global__ __launch_bounds__(512, 8) void kD(const float* __restrict__ out_W,
                                             const float* __restrict__ out_b,
                                             const float* __restrict__ hnew,
                                             float* __restrict__ ws) {
    __shared__ __align__(16) float shn[H];
    __shared__ float lds_log[56];
    const int tid = threadIdx.x, lane = tid & 63, wid = tid >> 6;  // 8 waves
    const int row0 = blockIdx.x * RPB;
    if (row0 >= V) {
        if (tid == 0) {
            ws[OFF_PAIR + 2 * blockIdx.x] = -INFINITY;
            ws[OFF_PAIR + 2 * blockIdx.x + 1] = 0.f;
        }
        return;
    }
    const int nrows = min(RPB, V - row0);
    for (int i = tid; i < H; i += 512) shn[i] = hnew[i];
    __syncthreads();
    for (int k = wid; k < nrows; k += 8) {
        const int r = row0 + k;
        float acc = wsum(dotN(out_W + (size_t)r * H, shn, lane, 4));
        if (lane == 0) {
            const float lg = acc + out_b[r];
            lds_log[k] = lg;
            ws[OFF_LOG + r] = lg;
        }
    }
    __syncthreads();
    if (wid == 0) {  // block (m,s) partial; nrows <= 50 < 64
        const float v = (lane < nrows) ? lds_log[lane] : -INFINITY;
        const float m = wmax(v);
        const float e = (lane < nrows) ? expf(v - m) : 0.f;
        const float s = wsum(e);
        if (lane == 0) {
            ws[OFF_PAIR + 2 * blockIdx.x] = m;
            ws[OFF_PAIR + 2 * blockIdx.x + 1] = s;
        }
    }
}

// ---- E: redundant (m,s) combine per block + log-softmax write -------------
__global__ __launch_bounds__(256) void kE(const float* __restrict__ ws,
                                          float* __restrict__ out) {
    const int tid = threadIdx.x, lane = tid & 63, wid = tid >> 6;
    float m = -INFINITY, s = 0.f;
    for (int i = tid; i < NBLKD; i += 256) {  // 4 iterations
        const float mi = ws[OFF_PAIR + 2 * i];
        const float si = ws[OFF_PAIR + 2 * i + 1];
        if (si > 0.f) msmerge(m, s, mi, si);
    }
#pragma unroll
    for (int off = 32; off > 0; off >>= 1) {
        const float mo = __shfl_xor(m, off);
        const float so = __shfl_xor(s, off);
        if (so > 0.f) msmerge(m, s, mo, so);
    }
    __shared__ float sm[4], ss[4], fin[2];
    if (lane == 0) { sm[wid] = m; ss[wid] = s; }
    __syncthreads();
    if (tid == 0) {
        float M = sm[0], S = ss[0];
        for (int i = 1; i < 4; ++i)
            if (ss[i] > 0.f) msmerge(M, S, sm[i], ss[i]);
        fin[0] = M;
        fin[1] = logf(S);
    }
    __syncthreads();
    const int i = blockIdx.x * 256 + tid;
    if (i < V) out[i] = ws[OFF_LOG + i] - fin[0] - fin[1];
}

extern "C" void kernel_launch(void* const* d_in, const int* in_sizes, int n_in,
                              void* d_out, int out_size, void* d_ws, size_t ws_size,
                              hipStream_t stream) {
    const long long* idx  = (const long long*)d_in[0];
    const float* hid    = (const float*)d_in[1];
    const float* enc    = (const float*)d_in[2];
    const float* emb    = (const float*)d_in[3];
    const float* attn_W = (const float*)d_in[4];
    const float* attn_b = (const float*)d_in[5];
    const float* comb_W = (const float*)d_in[6];
    const float* comb_b = (const float*)d_in[7];
    const float* w_ih   = (const float*)d_in[8];
    const float* w_hh   = (const float*)d_in[9];
    const float* b_ih   = (const float*)d_in[10];
    const float* b_hh   = (const float*)d_in[11];
    const float* out_W  = (const float*)d_in[12];
    const float* out_b  = (const float*)d_in[13];
    float* out = (float*)d_out;
    float* ws  = (float*)d_ws;

    kA<<<64 + 768, 256, 0, stream>>>(idx, hid, emb, attn_W, attn_b, w_hh, b_hh, ws);
    kB<<<256, 256, 0, stream>>>(idx, emb, enc, comb_W, comb_b, ws, out);
    kC<<<256, 768, 0, stream>>>(w_ih, b_ih, hid, ws, out);
    kD<<<NBLKD, 512, 0, stream>>>(out_W, out_b, out + V, ws);
    kE<<<(V + 255) / 256, 256, 0, stream>>>(ws, out);
}

// Round 9
// 57.420 us; speedup vs baseline: 1.5693x; 1.0055x over previous
//
#include <hip/hip_runtime.h>
#include <math.h>

constexpr int H = 1024;
constexpr int V = 50257;
constexpr int L = 64;

constexpr int NBLKD = 512;             // out-proj blocks (2/CU, one generation)

// ws float offsets
constexpr int OFF_ALOG = 0;            // 64 attention logits
constexpr int OFF_GH   = 64;           // 3072: gh = w_hh@h0 + b_hh
constexpr int OFF_X    = 64 + 3 * H;   // 1024: x = relu(comb)
constexpr int OFF_LOG  = OFF_X + H;    // V logits
constexpr int OFF_PAIR = OFF_LOG + V;  // 2*NBLKD (m,s) pairs

__device__ __forceinline__ float wsum(float v) {
#pragma unroll
    for (int off = 32; off > 0; off >>= 1) v += __shfl_xor(v, off);
    return v;
}
__device__ __forceinline__ float wmax(float v) {
#pragma unroll
    for (int off = 32; off > 0; off >>= 1) v = fmaxf(v, __shfl_xor(v, off));
    return v;
}

__device__ __forceinline__ float dot4(float4 a, float4 b) {
    return a.x * b.x + a.y * b.y + a.z * b.z + a.w * b.w;
}

__device__ __forceinline__ float dotN(const float* __restrict__ w,
                                      const float* __restrict__ v,
                                      int lane, int n4) { // n4 = N/256
    const float4* w4 = reinterpret_cast<const float4*>(w);
    const float4* v4 = reinterpret_cast<const float4*>(v);
    float acc = 0.f;
    for (int it = 0; it < n4; ++it)
        acc += dot4(w4[lane + it * 64], v4[lane + it * 64]);
    return acc;
}

// Two adjacent rows: 8 float4 global loads in flight before any use.
__device__ __forceinline__ void dot1024x2(const float* __restrict__ wa,
                                          const float* __restrict__ wb,
                                          const float* __restrict__ v,
                                          int lane, float& oa, float& ob) {
    const float4* a4 = reinterpret_cast<const float4*>(wa);
    const float4* b4 = reinterpret_cast<const float4*>(wb);
    const float4* v4 = reinterpret_cast<const float4*>(v);
    float sa = 0.f, sb = 0.f;
#pragma unroll
    for (int it = 0; it < 4; ++it) {
        const float4 x = a4[lane + it * 64];
        const float4 y = b4[lane + it * 64];
        const float4 u = v4[lane + it * 64];
        sa += dot4(x, u);
        sb += dot4(y, u);
    }
    oa = sa; ob = sb;
}

__device__ __forceinline__ void msmerge(float& m, float& s, float m2, float s2) {
    const float M = fmaxf(m, m2);
    s = s * expf(m - M) + s2 * expf(m2 - M);
    m = M;
}

// ---- A: attention logits (blocks 0..63) || gh GEMV (blocks 64..831) -------
__global__ __launch_bounds__(256) void kA(const long long* __restrict__ idx_p,
                                          const float* __restrict__ hid,
                                          const float* __restrict__ emb,
                                          const float* __restrict__ attn_W,
                                          const float* __restrict__ attn_b,
                                          const float* __restrict__ w_hh,
                                          const float* __restrict__ b_hh,
                                          float* __restrict__ ws) {
    const int tid = threadIdx.x;
    const int lane = tid & 63, wid = tid >> 6;
    if (blockIdx.x < 64) {
        const int l = blockIdx.x;
        const int idx = (int)idx_p[0];
        const float4* w4 = reinterpret_cast<const float4*>(attn_W + (size_t)l * (2 * H));
        const float4* e4 = reinterpret_cast<const float4*>(emb + (size_t)idx * H);
        const float4* h4 = reinterpret_cast<const float4*>(hid);
        float acc = dot4(w4[tid], e4[tid]) + dot4(w4[tid + 256], h4[tid]);
        acc = wsum(acc);
        __shared__ float sred[4];
        if (lane == 0) sred[wid] = acc;
        __syncthreads();
        if (tid == 0)
            ws[OFF_ALOG + l] = sred[0] + sred[1] + sred[2] + sred[3] + attn_b[l];
    } else {
        __shared__ __align__(16) float4 sv[256];
        sv[tid] = reinterpret_cast<const float4*>(hid)[tid];
        __syncthreads();
        const int row = (blockIdx.x - 64) * 4 + wid;  // 0..3071
        float acc = wsum(dotN(w_hh + (size_t)row * H,
                              reinterpret_cast<const float*>(sv), lane, 4));
        if (lane == 0) ws[OFF_GH + row] = acc + b_hh[row];
    }
}

// ---- B: softmax + attn_applied + xcat + comb GEMV (256 blocks) ------------
__global__ __launch_bounds__(256) void kB(const long long* __restrict__ idx_p,
                                          const float* __restrict__ emb,
                                          const float* __restrict__ enc,
                                          const float* __restrict__ comb_W,
                                          const float* __restrict__ comb_b,
                                          float* __restrict__ ws,
                                          float* __restrict__ out) {
    __shared__ float wls[L];
    __shared__ __align__(16) float4 sx[512];  // xcat: [embedded | attn_applied]
    const int tid = threadIdx.x;
    if (tid < L) {
        const float lg = ws[OFF_ALOG + tid];
        const float m = wmax(lg);
        const float e = expf(lg - m);
        const float s = wsum(e);
        wls[tid] = e / s;
        if (blockIdx.x == 0) out[V + H + tid] = e / s;
    }
    __syncthreads();
    const int idx = (int)idx_p[0];
    sx[tid] = reinterpret_cast<const float4*>(emb + (size_t)idx * H)[tid];
    {
        const float4* e4 = reinterpret_cast<const float4*>(enc);
        float4 a4 = {0.f, 0.f, 0.f, 0.f};
#pragma unroll 8
        for (int l = 0; l < L; ++l) {
            const float wl = wls[l];
            const float4 v = e4[l * 256 + tid];
            a4.x += wl * v.x; a4.y += wl * v.y;
            a4.z += wl * v.z; a4.w += wl * v.w;
        }
        sx[256 + tid] = a4;
    }
    __syncthreads();
    const int lane = tid & 63, wid = tid >> 6;
    const int row = blockIdx.x * 4 + wid;  // 0..1023
    float acc = wsum(dotN(comb_W + (size_t)row * (2 * H),
                          reinterpret_cast<const float*>(sx), lane, 8));
    if (lane == 0) ws[OFF_X + row] = fmaxf(acc + comb_b[row], 0.f);
}

// ---- C: gi GEMV + GRU gates fused (256 blocks x 768 threads) --------------
__global__ __launch_bounds__(768) void kC(const float* __restrict__ w_ih,
                                          const float* __restrict__ b_ih,
                                          const float* __restrict__ hid,
                                          float* __restrict__ ws,
                                          float* __restrict__ out) {
    __shared__ __align__(16) float4 sx4[256];  // x
    __shared__ float gi_s[12];
    const int tid = threadIdx.x;
    if (tid < 256) sx4[tid] = reinterpret_cast<const float4*>(ws + OFF_X)[tid];
    __syncthreads();
    const int lane = tid & 63, wid = tid >> 6;  // wid 0..11
    const int g = wid >> 2, i = wid & 3;
    const int row = g * H + blockIdx.x * 4 + i;
    float acc = wsum(dotN(w_ih + (size_t)row * H,
                          reinterpret_cast<const float*>(sx4), lane, 4));
    if (lane == 0) gi_s[wid] = acc + b_ih[row];
    __syncthreads();
    if (tid < 4) {
        const int t = blockIdx.x * 4 + tid;
        const float ir = gi_s[tid], iz = gi_s[4 + tid], in_ = gi_s[8 + tid];
        const float hr = ws[OFF_GH + t];
        const float hz = ws[OFF_GH + H + t];
        const float hn = ws[OFF_GH + 2 * H + t];
        const float r = 1.f / (1.f + expf(-(ir + hr)));
        const float z = 1.f / (1.f + expf(-(iz + hz)));
        const float n = tanhf(in_ + r * hn);
        out[V + t] = (1.f - z) * n + z * hid[t];
    }
}

// ---- D: out-proj GEMV. 512 blocks x 512 thr (2/CU), 2-row ILP per wave ----
// __launch_bounds__(512,4): VGPR cap 128 -> 8 float4 loads in flight/wave,
// 16 waves/CU, one block generation.
__global__ __launch_bounds__(512, 4) void kD(const float* __restrict__ out_W,
                                             const float* __restrict__ out_b,
                                             const float* __restrict__ hnew,
                                             float* __restrict__ ws) {
    __shared__ __align__(16) float shn[H];
    __shared__ float lds_log[104];
    const int tid = threadIdx.x, lane = tid & 63, wid = tid >> 6;  // 8 waves
    const int b = blockIdx.x;
    const int row0 = (int)(((long long)b * V) / NBLKD);
    const int row1 = (int)(((long long)(b + 1) * V) / NBLKD);
    const int nrows = row1 - row0;    // 98 or 99
    for (int i = tid; i < H; i += 512) shn[i] = hnew[i];
    __syncthreads();
    // wave wid handles row pairs (k, k+1), k = 2*wid + 16*j
    for (int k = 2 * wid; k < nrows; k += 16) {
        const int r0 = row0 + k;
        const int r1v = r0 + 1;
        const bool has2 = (k + 1) < nrows;
        const int r1 = has2 ? r1v : r0;
        float a0, a1;
        dot1024x2(out_W + (size_t)r0 * H, out_W + (size_t)r1 * H, shn, lane, a0, a1);
        a0 = wsum(a0); a1 = wsum(a1);
        if (lane == 0) {
            const float l0 = a0 + out_b[r0];
            lds_log[k] = l0;
            ws[OFF_LOG + r0] = l0;
            if (has2) {
                const float l1 = a1 + out_b[r1];
                lds_log[k + 1] = l1;
                ws[OFF_LOG + r1] = l1;
            }
        }
    }
    __syncthreads();
    if (wid == 0) {  // block (m,s) partial over nrows (<= 99 < 128)
        float v0 = (lane < nrows) ? lds_log[lane] : -INFINITY;
        float v1 = (64 + lane < nrows) ? lds_log[64 + lane] : -INFINITY;
        const float m = wmax(fmaxf(v0, v1));
        float e = 0.f;
        if (lane < nrows)      e += expf(v0 - m);
        if (64 + lane < nrows) e += expf(v1 - m);
        const float s = wsum(e);
        if (lane == 0) {
            ws[OFF_PAIR + 2 * b] = m;
            ws[OFF_PAIR + 2 * b + 1] = s;
        }
    }
}

// ---- E: redundant (m,s) combine per block + log-softmax write -------------
__global__ __launch_bounds__(256) void kE(const float* __restrict__ ws,
                                          float* __restrict__ out) {
    const int tid = threadIdx.x, lane = tid & 63, wid = tid >> 6;
    float m = -INFINITY, s = 0.f;
    for (int i = tid; i < NBLKD; i += 256) {  // 2 iterations
        const float mi = ws[OFF_PAIR + 2 * i];
        const float si = ws[OFF_PAIR + 2 * i + 1];
        if (si > 0.f) msmerge(m, s, mi, si);
    }
#pragma unroll
    for (int off = 32; off > 0; off >>= 1) {
        const float mo = __shfl_xor(m, off);
        const float so = __shfl_xor(s, off);
        if (so > 0.f) msmerge(m, s, mo, so);
    }
    __shared__ float sm[4], ss[4], fin[2];
    if (lane == 0) { sm[wid] = m; ss[wid] = s; }
    __syncthreads();
    if (tid == 0) {
        float M = sm[0], S = ss[0];
        for (int i = 1; i < 4; ++i)
            if (ss[i] > 0.f) msmerge(M, S, sm[i], ss[i]);
        fin[0] = M;
        fin[1] = logf(S);
    }
    __syncthreads();
    const int i = blockIdx.x * 256 + tid;
    if (i < V) out[i] = ws[OFF_LOG + i] - fin[0] - fin[1];
}

extern "C" void kernel_launch(void* const* d_in, const int* in_sizes, int n_in,
                              void* d_out, int out_size, void* d_ws, size_t ws_size,
                              hipStream_t stream) {
    const long long* idx  = (const long long*)d_in[0];
    const float* hid    = (const float*)d_in[1];
    const float* enc    = (const float*)d_in[2];
    const float* emb    = (const float*)d_in[3];
    const float* attn_W = (const float*)d_in[4];
    const float* attn_b = (const float*)d_in[5];
    const float* comb_W = (const float*)d_in[6];
    const float* comb_b = (const float*)d_in[7];
    const float* w_ih   = (const float*)d_in[8];
    const float* w_hh   = (const float*)d_in[9];
    const float* b_ih   = (const float*)d_in[10];
    const float* b_hh   = (const float*)d_in[11];
    const float* out_W  = (const float*)d_in[12];
    const float* out_b  = (const float*)d_in[13];
    float* out = (float*)d_out;
    float* ws  = (float*)d_ws;

    kA<<<64 + 768, 256, 0, stream>>>(idx, hid, emb, attn_W, attn_b, w_hh, b_hh, ws);
    kB<<<256, 256, 0, stream>>>(idx, emb, enc, comb_W, comb_b, ws, out);
    kC<<<256, 768, 0, stream>>>(w_ih, b_ih, hid, ws, out);
    kD<<<NBLKD, 512, 0, stream>>>(out_W, out_b, out + V, ws);
    kE<<<(V + 255) / 256, 256, 0, stream>>>(ws, out);
}

// Round 10
// 56.339 us; speedup vs baseline: 1.5994x; 1.0192x over previous
//
#include <hip/hip_runtime.h>
#include <math.h>

constexpr int H = 1024;
constexpr int V = 50257;
constexpr int L = 64;

constexpr int NBLKD = 512;             // out-proj blocks (2/CU, one generation)

// ws float offsets
constexpr int OFF_ALOG = 0;            // 64 attention logits
constexpr int OFF_GH   = 64;           // 3072: gh = w_hh@h0 + b_hh
constexpr int OFF_CP   = 64 + 3 * H;   // 1024: comb emb-half partial
constexpr int OFF_X    = OFF_CP + H;   // 1024: x = relu(comb)
constexpr int OFF_LOG  = OFF_X + H;    // V logits
constexpr int OFF_PAIR = OFF_LOG + V;  // 2*NBLKD (m,s) pairs

__device__ __forceinline__ float wsum(float v) {
#pragma unroll
    for (int off = 32; off > 0; off >>= 1) v += __shfl_xor(v, off);
    return v;
}
__device__ __forceinline__ float wmax(float v) {
#pragma unroll
    for (int off = 32; off > 0; off >>= 1) v = fmaxf(v, __shfl_xor(v, off));
    return v;
}

__device__ __forceinline__ float dot4(float4 a, float4 b) {
    return a.x * b.x + a.y * b.y + a.z * b.z + a.w * b.w;
}

__device__ __forceinline__ float dotN(const float* __restrict__ w,
                                      const float* __restrict__ v,
                                      int lane, int n4) { // n4 = N/256
    const float4* w4 = reinterpret_cast<const float4*>(w);
    const float4* v4 = reinterpret_cast<const float4*>(v);
    float acc = 0.f;
    for (int it = 0; it < n4; ++it)
        acc += dot4(w4[lane + it * 64], v4[lane + it * 64]);
    return acc;
}

__device__ __forceinline__ void msmerge(float& m, float& s, float m2, float s2) {
    const float M = fmaxf(m, m2);
    s = s * expf(m - M) + s2 * expf(m2 - M);
    m = M;
}

// ---- A: logits (blocks 0..63) || gh (64..831) || comb-emb-half (832..1087) -
__global__ __launch_bounds__(256) void kA(const long long* __restrict__ idx_p,
                                          const float* __restrict__ hid,
                                          const float* __restrict__ emb,
                                          const float* __restrict__ attn_W,
                                          const float* __restrict__ attn_b,
                                          const float* __restrict__ w_hh,
                                          const float* __restrict__ b_hh,
                                          const float* __restrict__ comb_W,
                                          float* __restrict__ ws) {
    const int tid = threadIdx.x;
    const int lane = tid & 63, wid = tid >> 6;
    const int b = blockIdx.x;
    if (b < 64) {
        const int l = b;
        const int idx = (int)idx_p[0];
        const float4* w4 = reinterpret_cast<const float4*>(attn_W + (size_t)l * (2 * H));
        const float4* e4 = reinterpret_cast<const float4*>(emb + (size_t)idx * H);
        const float4* h4 = reinterpret_cast<const float4*>(hid);
        float acc = dot4(w4[tid], e4[tid]) + dot4(w4[tid + 256], h4[tid]);
        acc = wsum(acc);
        __shared__ float sred[4];
        if (lane == 0) sred[wid] = acc;
        __syncthreads();
        if (tid == 0)
            ws[OFF_ALOG + l] = sred[0] + sred[1] + sred[2] + sred[3] + attn_b[l];
    } else if (b < 832) {
        __shared__ __align__(16) float4 sv[256];
        sv[tid] = reinterpret_cast<const float4*>(hid)[tid];
        __syncthreads();
        const int row = (b - 64) * 4 + wid;  // 0..3071
        float acc = wsum(dotN(w_hh + (size_t)row * H,
                              reinterpret_cast<const float*>(sv), lane, 4));
        if (lane == 0) ws[OFF_GH + row] = acc + b_hh[row];
    } else {
        __shared__ __align__(16) float4 se[256];
        const int idx = (int)idx_p[0];
        se[tid] = reinterpret_cast<const float4*>(emb + (size_t)idx * H)[tid];
        __syncthreads();
        const int row = (b - 832) * 4 + wid;  // 0..1023
        float acc = wsum(dotN(comb_W + (size_t)row * (2 * H),
                              reinterpret_cast<const float*>(se), lane, 4));
        if (lane == 0) ws[OFF_CP + row] = acc;   // no bias yet
    }
}

// ---- B: softmax + attn_applied + comb-attn-half -> x (256 blocks) ---------
__global__ __launch_bounds__(256) void kB(const float* __restrict__ enc,
                                          const float* __restrict__ comb_W,
                                          const float* __restrict__ comb_b,
                                          float* __restrict__ ws,
                                          float* __restrict__ out) {
    __shared__ float wls[L];
    __shared__ __align__(16) float4 sx[256];  // attn_applied
    const int tid = threadIdx.x;
    if (tid < L) {
        const float lg = ws[OFF_ALOG + tid];   // wave 0 holds all 64 logits
        const float m = wmax(lg);
        const float e = expf(lg - m);
        const float s = wsum(e);
        wls[tid] = e / s;
        if (blockIdx.x == 0) out[V + H + tid] = e / s;
    }
    __syncthreads();
    {
        const float4* e4 = reinterpret_cast<const float4*>(enc);
        float4 a4 = {0.f, 0.f, 0.f, 0.f};
#pragma unroll 8
        for (int l = 0; l < L; ++l) {
            const float wl = wls[l];
            const float4 v = e4[l * 256 + tid];
            a4.x += wl * v.x; a4.y += wl * v.y;
            a4.z += wl * v.z; a4.w += wl * v.w;
        }
        sx[tid] = a4;
    }
    __syncthreads();
    const int lane = tid & 63, wid = tid >> 6;
    const int row = blockIdx.x * 4 + wid;  // 0..1023
    float acc = wsum(dotN(comb_W + (size_t)row * (2 * H) + H,
                          reinterpret_cast<const float*>(sx), lane, 4));
    if (lane == 0)
        ws[OFF_X + row] = fmaxf(acc + ws[OFF_CP + row] + comb_b[row], 0.f);
}

// ---- C: gi GEMV + GRU gates fused (256 blocks x 768 threads) --------------
__global__ __launch_bounds__(768) void kC(const float* __restrict__ w_ih,
                                          const float* __restrict__ b_ih,
                                          const float* __restrict__ hid,
                                          float* __restrict__ ws,
                                          float* __restrict__ out) {
    __shared__ __align__(16) float4 sx4[256];  // x
    __shared__ float gi_s[12];
    const int tid = threadIdx.x;
    if (tid < 256) sx4[tid] = reinterpret_cast<const float4*>(ws + OFF_X)[tid];
    __syncthreads();
    const int lane = tid & 63, wid = tid >> 6;  // wid 0..11
    const int g = wid >> 2, i = wid & 3;
    const int row = g * H + blockIdx.x * 4 + i;
    float acc = wsum(dotN(w_ih + (size_t)row * H,
                          reinterpret_cast<const float*>(sx4), lane, 4));
    if (lane == 0) gi_s[wid] = acc + b_ih[row];
    __syncthreads();
    if (tid < 4) {
        const int t = blockIdx.x * 4 + tid;
        const float ir = gi_s[tid], iz = gi_s[4 + tid], in_ = gi_s[8 + tid];
        const float hr = ws[OFF_GH + t];
        const float hz = ws[OFF_GH + H + t];
        const float hn = ws[OFF_GH + 2 * H + t];
        const float r = 1.f / (1.f + expf(-(ir + hr)));
        const float z = 1.f / (1.f + expf(-(iz + hz)));
        const float n = tanhf(in_ + r * hn);
        out[V + t] = (1.f - z) * n + z * hid[t];
    }
}

// ---- D: out-proj GEMV. h_new in REGISTERS; loop = loads+FMA+reduce only ---
__global__ __launch_bounds__(512, 4) void kD(const float* __restrict__ out_W,
                                             const float* __restrict__ out_b,
                                             const float* __restrict__ hnew,
                                             float* __restrict__ ws) {
    __shared__ float lds_log[104];
    const int tid = threadIdx.x, lane = tid & 63, wid = tid >> 6;  // 8 waves
    const int b = blockIdx.x;
    const int row0 = (int)(((long long)b * V) / NBLKD);
    const int row1 = (int)(((long long)(b + 1) * V) / NBLKD);
    const int nrows = row1 - row0;    // 98 or 99
    // h_new fragment per lane: 16 VGPRs, loaded once (L2 serves duplicates)
    const float4* v4 = reinterpret_cast<const float4*>(hnew);
    const float4 hv0 = v4[lane], hv1 = v4[lane + 64];
    const float4 hv2 = v4[lane + 128], hv3 = v4[lane + 192];
    for (int k = 2 * wid; k < nrows; k += 16) {
        const int r0 = row0 + k;
        const bool has2 = (k + 1) < nrows;
        const int r1 = has2 ? r0 + 1 : r0;
        const float4* a4 = reinterpret_cast<const float4*>(out_W + (size_t)r0 * H);
        const float4* b4 = reinterpret_cast<const float4*>(out_W + (size_t)r1 * H);
        const float4 a0 = a4[lane], a1 = a4[lane + 64];
        const float4 a2 = a4[lane + 128], a3 = a4[lane + 192];
        const float4 b0 = b4[lane], b1 = b4[lane + 64];
        const float4 b2 = b4[lane + 128], b3 = b4[lane + 192];
        float sa = dot4(a0, hv0) + dot4(a1, hv1) + dot4(a2, hv2) + dot4(a3, hv3);
        float sb = dot4(b0, hv0) + dot4(b1, hv1) + dot4(b2, hv2) + dot4(b3, hv3);
        sa = wsum(sa); sb = wsum(sb);
        if (lane == 0) {
            const float l0 = sa + out_b[r0];
            lds_log[k] = l0;
            ws[OFF_LOG + r0] = l0;
            if (has2) {
                const float l1 = sb + out_b[r1];
                lds_log[k + 1] = l1;
                ws[OFF_LOG + r1] = l1;
            }
        }
    }
    __syncthreads();
    if (wid == 0) {  // block (m,s) partial over nrows (<= 99)
        float v0 = (lane < nrows) ? lds_log[lane] : -INFINITY;
        float v1 = (64 + lane < nrows) ? lds_log[64 + lane] : -INFINITY;
        const float m = wmax(fmaxf(v0, v1));
        float e = 0.f;
        if (lane < nrows)      e += expf(v0 - m);
        if (64 + lane < nrows) e += expf(v1 - m);
        const float s = wsum(e);
        if (lane == 0) {
            ws[OFF_PAIR + 2 * b] = m;
            ws[OFF_PAIR + 2 * b + 1] = s;
        }
    }
}

// ---- E: redundant (m,s) combine per block + log-softmax write -------------
__global__ __launch_bounds__(256) void kE(const float* __restrict__ ws,
                                          float* __restrict__ out) {
    const int tid = threadIdx.x, lane = tid & 63, wid = tid >> 6;
    float m = -INFINITY, s = 0.f;
    for (int i = tid; i < NBLKD; i += 256) {  // 2 iterations
        const float mi = ws[OFF_PAIR + 2 * i];
        const float si = ws[OFF_PAIR + 2 * i + 1];
        if (si > 0.f) msmerge(m, s, mi, si);
    }
#pragma unroll
    for (int off = 32; off > 0; off >>= 1) {
        const float mo = __shfl_xor(m, off);
        const float so = __shfl_xor(s, off);
        if (so > 0.f) msmerge(m, s, mo, so);
    }
    __shared__ float sm[4], ss[4], fin[2];
    if (lane == 0) { sm[wid] = m; ss[wid] = s; }
    __syncthreads();
    if (tid == 0) {
        float M = sm[0], S = ss[0];
        for (int i = 1; i < 4; ++i)
            if (ss[i] > 0.f) msmerge(M, S, sm[i], ss[i]);
        fin[0] = M;
        fin[1] = logf(S);
    }
    __syncthreads();
    const int i = blockIdx.x * 256 + tid;
    if (i < V) out[i] = ws[OFF_LOG + i] - fin[0] - fin[1];
}

extern "C" void kernel_launch(void* const* d_in, const int* in_sizes, int n_in,
                              void* d_out, int out_size, void* d_ws, size_t ws_size,
                              hipStream_t stream) {
    const long long* idx  = (const long long*)d_in[0];
    const float* hid    = (const float*)d_in[1];
    const float* enc    = (const float*)d_in[2];
    const float* emb    = (const float*)d_in[3];
    const float* attn_W = (const float*)d_in[4];
    const float* attn_b = (const float*)d_in[5];
    const float* comb_W = (const float*)d_in[6];
    const float* comb_b = (const float*)d_in[7];
    const float* w_ih   = (const float*)d_in[8];
    const float* w_hh   = (const float*)d_in[9];
    const float* b_ih   = (const float*)d_in[10];
    const float* b_hh   = (const float*)d_in[11];
    const float* out_W  = (const float*)d_in[12];
    const float* out_b  = (const float*)d_in[13];
    float* out = (float*)d_out;
    float* ws  = (float*)d_ws;

    kA<<<1088, 256, 0, stream>>>(idx, hid, emb, attn_W, attn_b, w_hh, b_hh,
                                 comb_W, ws);
    kB<<<256, 256, 0, stream>>>(enc, comb_W, comb_b, ws, out);
    kC<<<256, 768, 0, stream>>>(w_ih, b_ih, hid, ws, out);
    kD<<<NBLKD, 512, 0, stream>>>(out_W, out_b, out + V, ws);
    kE<<<(V + 255) / 256, 256, 0, stream>>>(ws, out);
}